// Round 2
// baseline (609.404 us; speedup 1.0000x reference)
//
#include <hip/hip_runtime.h>

using u16 = unsigned short;
using u32 = unsigned int;
typedef __attribute__((ext_vector_type(8))) __bf16 bf16x8;
typedef __attribute__((ext_vector_type(4))) float f32x4;

#define DEVI __device__ __forceinline__

constexpr int BN_ = 128;              // batch
constexpr int NN  = 1024;             // graph nodes
constexpr int CH  = 66;               // IN_DIM + HID
constexpr int HD  = 64;               // HID
constexpr int RR  = BN_ * CH;         // 8448 rows
constexpr int KTRUE = 330, KPAD = 352;
constexpr long M2 = (long)NN * NN;    // 1048576

DEVI float bf2f(u16 u) { u32 i = ((u32)u) << 16; float f; __builtin_memcpy(&f, &i, 4); return f; }
DEVI u16 f2bf(float f) { u32 i; __builtin_memcpy(&i, &f, 4); i += 0x7fffu + ((i >> 16) & 1u); return (u16)(i >> 16); }

DEVI void gl_lds16(const void* g, void* l) {
  __builtin_amdgcn_global_load_lds((const __attribute__((address_space(1))) u32*)g,
                                   (__attribute__((address_space(3))) u32*)l, 16, 0, 0);
}

// ---- GEMM:  acc[r,col] = sum_n X[r,n]*A[col,n]  (A given row-major [col][n])
// SQ=false: write into hT[(b*NN+col)*KPAD + 66*(z+1) + f]   (r = b*66+f)
// SQ=true : write Y[r*NN+col] = 2*acc - (r==col)            (B2 = 2*A*A - I)
template<bool SQ>
__global__ __launch_bounds__(256, 2)
void gemm_h(const u16* __restrict__ Xb, long xzs,
            const u16* __restrict__ Ab, long azs,
            u16* __restrict__ outp, long ozs)
{
  __shared__ u16 Xs[128 * 32];
  __shared__ u16 Bs[128 * 32];
  const int z = blockIdx.z;
  const u16* X = Xb + (long)z * xzs;
  const u16* A = Ab + (long)z * azs;
  const int tm = blockIdx.y, tn = blockIdx.x;
  const int tid = threadIdx.x, wv = tid >> 6, ln = tid & 63;

  const int r0  = wv * 16 + (ln >> 2);
  const int kch = (((ln & 3) ^ ((r0 >> 1) & 3))) * 8;
  const u16* gX = X + (long)(tm * 128 + r0) * NN + kch;
  const u16* gA = A + (long)(tn * 128 + r0) * NN + kch;
  u16* lX = &Xs[wv * 512];
  u16* lA = &Bs[wv * 512];

  const int frow = ln & 15;
  const int fk   = ((ln >> 4) ^ ((ln >> 1) & 3)) * 8;
  const int wr = wv >> 1, wc = wv & 1;

  f32x4 acc[4][4] = {};

  for (int k0 = 0; k0 < NN; k0 += 32) {
    gl_lds16(gX + k0,            lX);
    gl_lds16(gX + k0 + 64 * NN,  lX + 2048);
    gl_lds16(gA + k0,            lA);
    gl_lds16(gA + k0 + 64 * NN,  lA + 2048);
    __syncthreads();
    bf16x8 af[4], bfv[4];
#pragma unroll
    for (int m = 0; m < 4; m++) af[m]  = *(const bf16x8*)&Xs[(wr * 64 + m * 16 + frow) * 32 + fk];
#pragma unroll
    for (int n = 0; n < 4; n++) bfv[n] = *(const bf16x8*)&Bs[(wc * 64 + n * 16 + frow) * 32 + fk];
#pragma unroll
    for (int m = 0; m < 4; m++)
#pragma unroll
      for (int n = 0; n < 4; n++)
        acc[m][n] = __builtin_amdgcn_mfma_f32_16x16x32_bf16(af[m], bfv[n], acc[m][n], 0, 0, 0);
    __syncthreads();
  }

  // C/D layout: col = lane&15, row = (lane>>4)*4 + q
  const int colb = tn * 128 + wc * 64 + frow;
  const int rowb = tm * 128 + wr * 64 + (ln >> 4) * 4;
  if (SQ) {
    u16* Y = outp + (long)z * ozs;
#pragma unroll
    for (int m = 0; m < 4; m++)
#pragma unroll
      for (int n = 0; n < 4; n++) {
        const int col = colb + n * 16;
#pragma unroll
        for (int q = 0; q < 4; q++) {
          const int r = rowb + m * 16 + q;
          const float v = 2.0f * acc[m][n][q] - (r == col ? 1.0f : 0.0f);
          Y[(long)r * NN + col] = f2bf(v);
        }
      }
  } else {
    const int cb = 66 * (z + 1);
#pragma unroll
    for (int m = 0; m < 4; m++)
#pragma unroll
      for (int n = 0; n < 4; n++) {
        const int col = colb + n * 16;
#pragma unroll
        for (int q = 0; q < 4; q++) {
          const int r = rowb + m * 16 + q;
          const int b = r / 66, f = r - b * 66;
          outp[(long)(b * NN + col) * KPAD + cb + f] = f2bf(acc[m][n][q]);
        }
      }
  }
}

// ---- streaming projection: out[o, (b,ncol)] = act( W[o,:] . hT[(b,ncol),:] + bias )
// No LDS, no syncthreads. Wave owns 64 cols x full O. grid (4, B), 256 thr.
template<int O, bool FINAL>
__global__ __launch_bounds__(256)
void proj_s(const u16* __restrict__ hT, const u16* __restrict__ W,
            const float* __restrict__ bias, const float* __restrict__ hx,
            u16* __restrict__ xcrow, u16* __restrict__ hT2,
            float* __restrict__ ubuf, float* __restrict__ outp)
{
  const int b = blockIdx.y;
  const int tid = threadIdx.x, wv = tid >> 6, ln = tid & 63;
  const int nc0 = blockIdx.x * 256 + wv * 64;
  const int frow = ln & 15, fk8 = (ln >> 4) * 8;
  constexpr int FO = O / 16;
  f32x4 acc[FO][4] = {};

  const u16* hb0 = hT + (long)(b * NN + nc0 +  0 + frow) * KPAD + fk8;
  const u16* hb1 = hT + (long)(b * NN + nc0 + 16 + frow) * KPAD + fk8;
  const u16* hb2 = hT + (long)(b * NN + nc0 + 32 + frow) * KPAD + fk8;
  const u16* hb3 = hT + (long)(b * NN + nc0 + 48 + frow) * KPAD + fk8;
  const u16* wb  = W + frow * KPAD + fk8;

  for (int k0 = 0; k0 < KPAD; k0 += 32) {
    bf16x8 bt0 = *(const bf16x8*)(hb0 + k0);
    bf16x8 bt1 = *(const bf16x8*)(hb1 + k0);
    bf16x8 bt2 = *(const bf16x8*)(hb2 + k0);
    bf16x8 bt3 = *(const bf16x8*)(hb3 + k0);
#pragma unroll
    for (int m = 0; m < FO; m++) {
      bf16x8 aw = *(const bf16x8*)(wb + m * 16 * KPAD + k0);
      acc[m][0] = __builtin_amdgcn_mfma_f32_16x16x32_bf16(aw, bt0, acc[m][0], 0, 0, 0);
      acc[m][1] = __builtin_amdgcn_mfma_f32_16x16x32_bf16(aw, bt1, acc[m][1], 0, 0, 0);
      acc[m][2] = __builtin_amdgcn_mfma_f32_16x16x32_bf16(aw, bt2, acc[m][2], 0, 0, 0);
      acc[m][3] = __builtin_amdgcn_mfma_f32_16x16x32_bf16(aw, bt3, acc[m][3], 0, 0, 0);
    }
  }

  const int orow = (ln >> 4) * 4;
#pragma unroll
  for (int m = 0; m < FO; m++)
#pragma unroll
    for (int nf = 0; nf < 4; nf++) {
      const int ncol = nc0 + nf * 16 + frow;
#pragma unroll
      for (int q = 0; q < 4; q++) {
        const int o = m * 16 + orow + q;
        const float pre = acc[m][nf][q] + bias[o];
        if (!FINAL) {
          const float s = 1.0f / (1.0f + __expf(-pre));
          if (m < 4) {         // o < 64 : r-gate -> bf16(r*hx) into XC row + hT2 col
            const float hv = hx[(long)(b * HD + o) * NN + ncol];
            const u16 rv = f2bf(s * hv);
            xcrow[(long)(b * CH + 2 + o) * NN + ncol] = rv;
            hT2[(long)(b * NN + ncol) * KPAD + 2 + o] = rv;
          } else {             // o >= 64 : u-gate -> f32 (stored in d_out, reread by proj2)
            ubuf[(long)(b * HD + (o - HD)) * NN + ncol] = s;
          }
        } else {
          const float e  = __expf(2.0f * pre);
          const float cc = 1.0f - 2.0f / (e + 1.0f);     // tanh
          const long oi = (long)(b * HD + o) * NN + ncol;
          const float u = ubuf[oi];
          outp[oi] = u * hx[oi] + (1.0f - u) * cc;
        }
      }
    }
}

// ---- X row-layout build: X = bf16([inputs; hx]); XC input channels ----
__global__ void build_x(const float* __restrict__ inp, const float* __restrict__ hx,
                        u16* __restrict__ X, u16* __restrict__ XC)
{
  const int row = blockIdx.x;           // 0..8447
  const int b = row / 66, f = row - b * 66;
  const int n0 = threadIdx.x * 4;
  const float* s = (f < 2) ? (inp + (long)(b * 2 + f) * NN) : (hx + (long)(b * HD + f - 2) * NN);
  const float4 v = *(const float4*)(s + n0);
  ushort4 o;
  o.x = f2bf(v.x); o.y = f2bf(v.y); o.z = f2bf(v.z); o.w = f2bf(v.w);
  *(ushort4*)&X[(long)row * NN + n0] = o;
  if (f < 2) *(ushort4*)&XC[(long)row * NN + n0] = o;
}

// ---- transposed channels: hT1 c=0..65 ([inputs;hx]^T), hT2 c=0..1 (inputs^T) ----
__global__ void xposeX(const float* __restrict__ inp, const float* __restrict__ hx,
                       u16* __restrict__ hT1, u16* __restrict__ hT2)
{
  const int b = blockIdx.y;
  const int ncol = blockIdx.x * 64 + (threadIdx.x >> 2);
  const int j = threadIdx.x & 3;
  const long cbase = (long)(b * NN + ncol) * KPAD;
#pragma unroll
  for (int jj = 0; jj < 9; jj++) {
    const int j4 = jj * 4 + j;
    if (j4 < 33) {
      const int c0 = j4 * 2;
      const float v0 = (c0 < 2) ? inp[(long)(b * 2 + c0) * NN + ncol]
                                : hx[(long)(b * HD + c0 - 2) * NN + ncol];
      const float v1 = (c0 == 0) ? inp[(long)(b * 2 + 1) * NN + ncol]
                                 : hx[(long)(b * HD + c0 - 1) * NN + ncol];
      const u32 w = (u32)f2bf(v0) | ((u32)f2bf(v1) << 16);
      *(u32*)&hT1[cbase + c0] = w;
      if (j4 == 0) *(u32*)&hT2[cbase] = w;
    }
  }
}

// ---- A (f32, [m][n]) -> AT (bf16, [n][m]) for the A^2 GEMM ----
__global__ void xposeA(const float* __restrict__ A0, const float* __restrict__ A1,
                       u16* __restrict__ AT)
{
  __shared__ float Ls[64][65];
  const int z = blockIdx.z;
  const float* A = z ? A1 : A0;
  u16* out = AT + (long)z * M2;
  const int m0 = blockIdx.y * 64, n0 = blockIdx.x * 64;
  const int t = threadIdx.x;
  const int rr = t >> 6, cc = t & 63;
#pragma unroll
  for (int i = 0; i < 16; i++)
    Ls[i * 4 + rr][cc] = A[(long)(m0 + i * 4 + rr) * NN + n0 + cc];
  __syncthreads();
  const int n = t >> 2, mc = (t & 3) * 16;
  u16 tmp[16];
#pragma unroll
  for (int k = 0; k < 16; k++) tmp[k] = f2bf(Ls[mc + k][n]);
  u16* dst = &out[(long)(n0 + n) * NN + m0 + mc];
  *(ushort4*)(dst + 0)  = *(ushort4*)&tmp[0];
  *(ushort4*)(dst + 4)  = *(ushort4*)&tmp[4];
  *(ushort4*)(dst + 8)  = *(ushort4*)&tmp[8];
  *(ushort4*)(dst + 12) = *(ushort4*)&tmp[12];
}

// ---- convert A0->slot0, A1->slot2 of Abf2; pad+convert W's ----
__global__ void prep(const float* __restrict__ A0, const float* __restrict__ A1,
                     const float* __restrict__ Wru, const float* __restrict__ WC,
                     u16* __restrict__ Abf2, u16* __restrict__ Wrub, u16* __restrict__ WCb)
{
  const int gid = blockIdx.x * 256 + threadIdx.x;
  if (gid < 524288) {
    const bool sec = gid >= 262144;
    const float* s = sec ? (A1 + (long)(gid - 262144) * 4) : (A0 + (long)gid * 4);
    u16* d = sec ? (Abf2 + 2 * M2 + (long)(gid - 262144) * 4) : (Abf2 + (long)gid * 4);
    const float4 v = *(const float4*)s;
    ushort4 o; o.x = f2bf(v.x); o.y = f2bf(v.y); o.z = f2bf(v.z); o.w = f2bf(v.w);
    *(ushort4*)d = o;
  } else if (gid < 524288 + 128 * KPAD) {
    const int g = gid - 524288;
    const int o = g / KPAD, c = g - o * KPAD;
    Wrub[g] = f2bf(c < KTRUE ? Wru[o * KTRUE + c] : 0.0f);
  } else if (gid < 524288 + 128 * KPAD + 64 * KPAD) {
    const int g = gid - 524288 - 128 * KPAD;
    const int o = g / KPAD, c = g - o * KPAD;
    WCb[g] = f2bf(c < KTRUE ? WC[o * KTRUE + c] : 0.0f);
  }
}

extern "C" void kernel_launch(void* const* d_in, const int* in_sizes, int n_in,
                              void* d_out, int out_size, void* d_ws, size_t ws_size,
                              hipStream_t stream)
{
  const float* inp = (const float*)d_in[0];
  const float* hx  = (const float*)d_in[1];
  const float* A0  = (const float*)d_in[2];
  const float* A1  = (const float*)d_in[3];
  const float* Wru = (const float*)d_in[4];
  const float* bru = (const float*)d_in[5];
  const float* WC  = (const float*)d_in[6];
  const float* bC  = (const float*)d_in[7];
  float* out = (float*)d_out;

  char* ws = (char*)d_ws;
  u16* Abf2 = (u16*)(ws);                 //  8,388,608 B  [A0, B2_0, A1, B2_1]
  u16* ATbf = (u16*)(ws + 8388608);       //  4,194,304 B  [A0^T, A1^T]
  u16* Wrub = (u16*)(ws + 12582912);      //     90,112 B  (128x352)
  u16* WCb  = (u16*)(ws + 12673024);      //     45,056 B  (64x352)
  u16* X    = (u16*)(ws + 12718080);      // 17,301,504 B  (8448x1024 bf16 rows)
  u16* XC   = (u16*)(ws + 30019584);      // 17,301,504 B
  u16* hT1  = (u16*)(ws + 47321088);      // 92,274,688 B  (131072 x 352 bf16)
  u16* hT2  = (u16*)(ws + 139595776);     // 92,274,688 B  -> total 231,870,464 B
  float* ub = out;                        // u-gate parked in d_out between proj1/proj2

  prep<<<2312, 256, 0, stream>>>(A0, A1, Wru, WC, Abf2, Wrub, WCb);
  xposeA<<<dim3(16, 16, 2), 256, 0, stream>>>(A0, A1, ATbf);
  build_x<<<RR, 256, 0, stream>>>(inp, hx, X, XC);
  xposeX<<<dim3(16, BN_), 256, 0, stream>>>(inp, hx, hT1, hT2);

  // B2_z = 2*A_z*A_z - I   (written into Abf2 slots 1 and 3)
  gemm_h<true><<<dim3(8, 8, 2), 256, 0, stream>>>(Abf2, 2 * M2, ATbf, M2, Abf2 + M2, 2 * M2);

  // round 1: hT1 channels 66.. = [X*A0^T, X*B2_0^T, X*A1^T, X*B2_1^T]
  gemm_h<false><<<dim3(8, 66, 4), 256, 0, stream>>>(X, 0, Abf2, M2, hT1, 0);
  proj_s<128, false><<<dim3(4, BN_), 256, 0, stream>>>(hT1, Wrub, bru, hx, XC, hT2, ub, nullptr);

  // round 2
  gemm_h<false><<<dim3(8, 66, 4), 256, 0, stream>>>(XC, 0, Abf2, M2, hT2, 0);
  proj_s<64, true><<<dim3(4, BN_), 256, 0, stream>>>(hT2, WCb, bC, hx, nullptr, nullptr, ub, out);
}

// Round 4
// 486.774 us; speedup vs baseline: 1.2519x; 1.2519x over previous
//
#include <hip/hip_runtime.h>

using u16 = unsigned short;
using u32 = unsigned int;
typedef __attribute__((ext_vector_type(8))) __bf16 bf16x8;
typedef __attribute__((ext_vector_type(8))) u16 u16x8;
typedef __attribute__((ext_vector_type(4))) float f32x4;

#define DEVI __device__ __forceinline__

constexpr int BN_ = 128;              // batch
constexpr int NN  = 1024;             // graph nodes
constexpr int CH  = 66;               // IN_DIM + HID
constexpr int HD  = 64;               // HID
constexpr int RR  = BN_ * CH;         // 8448 rows
constexpr long RN = (long)RR * NN;    // elements per part
constexpr int KTRUE = 330, KPAD = 352;
constexpr long M2 = (long)NN * NN;

DEVI float bf2f(u16 u) { u32 i = ((u32)u) << 16; float f; __builtin_memcpy(&f, &i, 4); return f; }
DEVI u16 f2bf(float f) { u32 i; __builtin_memcpy(&i, &f, 4); i += 0x7fffu + ((i >> 16) & 1u); return (u16)(i >> 16); }

DEVI void gl_lds16(const void* g, void* l) {
  __builtin_amdgcn_global_load_lds((const __attribute__((address_space(1))) u32*)g,
                                   (__attribute__((address_space(3))) u32*)l, 16, 0, 0);
}

// ---- GEMM:  Y[r,m] = sum_n X[r,n]*A[m,n]   (CHEB: Y = 2*that - X0) ----
// VALIDATED round-1 kernel (68us/dispatch, coalesced epilogue). Do not touch.
template<bool CHEB>
__global__ __launch_bounds__(256, 2)
void gemm_bt(const u16* __restrict__ Xb, long xz,
             const u16* __restrict__ Ab,
             const u16* __restrict__ X0,
             u16* __restrict__ Yb, long yz)
{
  __shared__ u16 Xs[128 * 32];
  __shared__ u16 Bs[128 * 32];
  const int z = blockIdx.z;
  const u16* X = Xb + (long)z * xz;
  const u16* A = Ab + (long)z * M2;
  u16*       Y = Yb + (long)z * yz;
  const int tm = blockIdx.y, tn = blockIdx.x;
  const int tid = threadIdx.x, wv = tid >> 6, ln = tid & 63;

  const int r0  = wv * 16 + (ln >> 2);
  const int kch = (((ln & 3) ^ ((r0 >> 1) & 3))) * 8;
  const u16* gX = X + (long)(tm * 128 + r0) * NN + kch;
  const u16* gA = A + (long)(tn * 128 + r0) * NN + kch;
  u16* lX = &Xs[wv * 512];
  u16* lA = &Bs[wv * 512];

  const int frow = ln & 15;
  const int fk   = ((ln >> 4) ^ ((ln >> 1) & 3)) * 8;
  const int wr = wv >> 1, wc = wv & 1;

  f32x4 acc[4][4] = {};

  for (int k0 = 0; k0 < NN; k0 += 32) {
    gl_lds16(gX + k0,            lX);
    gl_lds16(gX + k0 + 64 * NN,  lX + 2048);
    gl_lds16(gA + k0,            lA);
    gl_lds16(gA + k0 + 64 * NN,  lA + 2048);
    __syncthreads();
    bf16x8 af[4], bfv[4];
#pragma unroll
    for (int m = 0; m < 4; m++) af[m]  = *(const bf16x8*)&Xs[(wr * 64 + m * 16 + frow) * 32 + fk];
#pragma unroll
    for (int n = 0; n < 4; n++) bfv[n] = *(const bf16x8*)&Bs[(wc * 64 + n * 16 + frow) * 32 + fk];
#pragma unroll
    for (int m = 0; m < 4; m++)
#pragma unroll
      for (int n = 0; n < 4; n++)
        acc[m][n] = __builtin_amdgcn_mfma_f32_16x16x32_bf16(af[m], bfv[n], acc[m][n], 0, 0, 0);
    __syncthreads();
  }

  const int colb = tn * 128 + wc * 64 + frow;
  const int rowb = tm * 128 + wr * 64 + (ln >> 4) * 4;
#pragma unroll
  for (int m = 0; m < 4; m++)
#pragma unroll
    for (int n = 0; n < 4; n++) {
      const int col = colb + n * 16;
#pragma unroll
      for (int q = 0; q < 4; q++) {
        const long r = rowb + m * 16 + q;
        float v = acc[m][n][q];
        if (CHEB) v = 2.0f * v - bf2f(X0[r * NN + col]);
        Y[r * NN + col] = f2bf(v);
      }
    }
}

// ---- transpose h (row-major parts [c][n]) -> hTg[(b,n)][352] (c-contiguous) ----
// grid (16 nblk, 128 b), 256 thr. Two n-halves of 32 cols each.
// LA (c-major: 352c x 32n, 22528B at byte 0); LB (n-major: 32n x 720B at byte 23040).
__global__ __launch_bounds__(256, 2)
void xpose_h(const u16* __restrict__ part0, const u16* __restrict__ Yb,
             const u16* __restrict__ zpad, u16* __restrict__ hTg)
{
  __shared__ u16 L[23040];   // 46080 B
  const int b = blockIdx.y, n0 = blockIdx.x * 64;
  const int tid = threadIdx.x, wv = tid >> 6, ln = tid & 63;

  for (int hf = 0; hf < 2; ++hf) {
    // Phase A: stage c-major. 22 x 1KB chunks; chunk i: c-rows 16i..16i+15, 64B each.
#pragma unroll
    for (int ii = 0; ii < 6; ++ii) {
      const int i = ii * 4 + wv;
      if (i < 22) {
        const int c = 16 * i + (ln >> 2);
        const int nsub = (ln & 3) * 8;
        const u16* src;
        if (c < KTRUE) {
          const int p = c / 66, f = c - 66 * p;
          const u16* base = (p == 0) ? part0 : (Yb + (long)(p - 1) * RN);
          src = base + (long)(b * CH + f) * NN + n0 + hf * 32 + nsub;
        } else {
          src = zpad;
        }
        gl_lds16(src, (char*)L + i * 1024);
      }
    }
    __syncthreads();

    // Phase B: gather 8 c per thread, write b128 into LB[n][c-chunk].
#pragma unroll
    for (int it = 0; it < 6; ++it) {
      const int q = it * 256 + tid;
      if (q < 1408) {                       // 32n x 44 chunks
        const int n = q & 31, cch = q >> 5;
        u16x8 v;
#pragma unroll
        for (int j = 0; j < 8; ++j) v[j] = L[(cch * 8 + j) * 32 + n];
        *(u16x8*)((char*)L + 23040 + n * 720 + cch * 16) = v;
      }
    }
    __syncthreads();

    // Phase C: stream LB out coalesced. 1408 x 16B.
#pragma unroll
    for (int it = 0; it < 6; ++it) {
      const int q = it * 256 + tid;
      if (q < 1408) {
        const int p = q * 16;
        const int n = p / 704, coff = p - n * 704;
        const u16x8 v = *(const u16x8*)((char*)L + 23040 + n * 720 + coff);
        *(u16x8*)((char*)hTg + (long)(b * NN + n0 + hf * 32 + n) * 704 + coff) = v;
      }
    }
    __syncthreads();
  }
}

// ---- projection from hTg: out[o,(b,n)] = act( W[o,:].hT[(b,n),:] + bias[o] ) ----
// grid (16, 128), 512 thr. Stage 64 rows x 704B (+16B pad -> 720B stride) via gl_lds16.
// 720B stride = 20 banks mod 32 -> frag ds_read_b128 is ~2-way (free).
template<int O, bool FINAL>
__global__ __launch_bounds__(512)
void proj_g(const u16* __restrict__ hTg, const u16* __restrict__ W,
            const float* __restrict__ bias, const float* __restrict__ hx,
            const u16* __restrict__ zpad, u16* __restrict__ xcrow,
            float* __restrict__ ubuf, float* __restrict__ outp)
{
  __shared__ u16 LS[23040];   // 64 x 720B
  const int b = blockIdx.y, n0 = blockIdx.x * 64;
  const int tid = threadIdx.x, wv = tid >> 6, ln = tid & 63;

  // stage: 45 x 1KB chunks
#pragma unroll
  for (int ii = 0; ii < 6; ++ii) {
    const int i = ii * 8 + wv;
    if (i < 45) {
      const int pos = i * 1024 + ln * 16;
      const int row = pos / 720, off = pos - row * 720;
      const u16* src = (off < 704)
        ? (hTg + (long)(b * NN + n0 + row) * KPAD + (off >> 1))
        : zpad;
      gl_lds16(src, (char*)LS + i * 1024);
    }
  }

  const int of  = (O == 128) ? wv : (wv >> 1);
  const int nfb = (O == 128) ? 0  : 2 * (wv & 1);
  constexpr int NF = (O == 128) ? 4 : 2;
  const int frow = ln & 15, klane = ln >> 4;
  const u16* wb = W + (long)(of * 16 + frow) * KPAD + klane * 8;

  // preload W frags to regs (overlaps with staging latency)
  bf16x8 wf[11];
#pragma unroll
  for (int t = 0; t < 11; ++t) wf[t] = *(const bf16x8*)(wb + t * 32);

  __syncthreads();

  f32x4 acc[NF] = {};
#pragma unroll
  for (int t = 0; t < 11; ++t) {
#pragma unroll
    for (int j = 0; j < NF; ++j) {
      const int nf = nfb + j;
      const bf16x8 bt = *(const bf16x8*)((char*)LS + (nf * 16 + frow) * 720 + t * 64 + klane * 16);
      acc[j] = __builtin_amdgcn_mfma_f32_16x16x32_bf16(wf[t], bt, acc[j], 0, 0, 0);
    }
  }

  const int orow = klane * 4;
#pragma unroll
  for (int j = 0; j < NF; ++j) {
    const int nf = nfb + j;
    const int ncol = n0 + nf * 16 + frow;
#pragma unroll
    for (int q = 0; q < 4; ++q) {
      const int o = of * 16 + orow + q;
      const float pre = acc[j][q] + bias[o];
      if (!FINAL) {
        const float sg = 1.0f / (1.0f + __expf(-pre));
        if (o < HD) {        // r-gate -> bf16(r*hx) into XC rows
          const float hv = hx[(long)(b * HD + o) * NN + ncol];
          xcrow[(long)(b * CH + 2 + o) * NN + ncol] = f2bf(sg * hv);
        } else {             // u-gate -> f32 (parked in d_out, reread by proj2)
          ubuf[(long)(b * HD + (o - HD)) * NN + ncol] = sg;
        }
      } else {
        const float e  = __expf(2.0f * pre);
        const float cc = 1.0f - 2.0f / (e + 1.0f);   // tanh(pre)
        const long oi = (long)(b * HD + o) * NN + ncol;
        const float u = ubuf[oi];
        outp[oi] = u * hx[oi] + (1.0f - u) * cc;
      }
    }
  }
}

// ---- build X = bf16([inputs; hx]) rows; also seed XC's input channels ----
__global__ void build_x(const float* __restrict__ inp, const float* __restrict__ hx,
                        u16* __restrict__ X, u16* __restrict__ XC)
{
  const int row = blockIdx.x;
  const int b = row / 66, f = row - b * 66;
  const int n0 = threadIdx.x * 4;
  const float* s = (f < 2) ? (inp + (long)(b * 2 + f) * NN) : (hx + (long)(b * HD + f - 2) * NN);
  const float4 v = *(const float4*)(s + n0);
  ushort4 o;
  o.x = f2bf(v.x); o.y = f2bf(v.y); o.z = f2bf(v.z); o.w = f2bf(v.w);
  *(ushort4*)&X[(long)row * NN + n0] = o;
  if (f < 2) *(ushort4*)&XC[(long)row * NN + n0] = o;
}

// ---- convert A0,A1 -> bf16; pad+convert W_ru,W_C to [O][352] bf16 ----
__global__ void prep(const float* __restrict__ A0, const float* __restrict__ A1,
                     const float* __restrict__ Wru, const float* __restrict__ WC,
                     u16* __restrict__ Abf, u16* __restrict__ Wrub, u16* __restrict__ WCb)
{
  const int gid = blockIdx.x * 256 + threadIdx.x;
  if (gid < 524288) {
    const float* s = (gid < 262144) ? (A0 + (long)gid * 4) : (A1 + (long)(gid - 262144) * 4);
    const float4 v = *(const float4*)s;
    ushort4 o; o.x = f2bf(v.x); o.y = f2bf(v.y); o.z = f2bf(v.z); o.w = f2bf(v.w);
    *(ushort4*)&Abf[(long)gid * 4] = o;
  } else if (gid < 524288 + 128 * KPAD) {
    const int g = gid - 524288;
    const int o = g / KPAD, c = g - o * KPAD;
    Wrub[g] = f2bf(c < KTRUE ? Wru[o * KTRUE + c] : 0.0f);
  } else if (gid < 524288 + 128 * KPAD + 64 * KPAD) {
    const int g = gid - 524288 - 128 * KPAD;
    const int o = g / KPAD, c = g - o * KPAD;
    WCb[g] = f2bf(c < KTRUE ? WC[o * KTRUE + c] : 0.0f);
  }
}

extern "C" void kernel_launch(void* const* d_in, const int* in_sizes, int n_in,
                              void* d_out, int out_size, void* d_ws, size_t ws_size,
                              hipStream_t stream)
{
  const float* inp = (const float*)d_in[0];
  const float* hx  = (const float*)d_in[1];
  const float* A0  = (const float*)d_in[2];
  const float* A1  = (const float*)d_in[3];
  const float* Wru = (const float*)d_in[4];
  const float* bru = (const float*)d_in[5];
  const float* WC  = (const float*)d_in[6];
  const float* bC  = (const float*)d_in[7];
  float* out = (float*)d_out;

  char* ws = (char*)d_ws;
  u16* Abf  = (u16*)(ws);                 //  4,194,304 B  [A0, A1] bf16
  u16* Wrub = (u16*)(ws + 4194304);       //     90,112 B  (128x352)
  u16* WCb  = (u16*)(ws + 4284416);       //     45,056 B  (64x352)
  u16* zpad = (u16*)(ws + 4329472);       //        256 B  zeros
  u16* X    = (u16*)(ws + 4329728);       // 17,301,504 B  (8448x1024 bf16 rows)
  u16* XC   = (u16*)(ws + 21631232);      // 17,301,504 B
  u16* Yb   = (u16*)(ws + 38932736);      // 69,206,016 B  (4 parts)
  u16* hTg  = (u16*)(ws + 108138752);     // 92,274,688 B  -> total 200,413,440 B
  float* ub = out;                        // u-gate parked in d_out between proj1/proj2

  hipMemsetAsync(zpad, 0, 256, stream);
  prep<<<2312, 256, 0, stream>>>(A0, A1, Wru, WC, Abf, Wrub, WCb);
  build_x<<<RR, 256, 0, stream>>>(inp, hx, X, XC);

  const dim3 gg(8, 66, 2);
  const dim3 gx(16, BN_);
  // round 1: parts [Y1_0, Y2_0, Y1_1, Y2_1]
  gemm_bt<false><<<gg, 256, 0, stream>>>(X, 0, Abf, nullptr, Yb, 2 * RN);
  gemm_bt<true ><<<gg, 256, 0, stream>>>(Yb, 2 * RN, Abf, X, Yb + RN, 2 * RN);
  xpose_h<<<gx, 256, 0, stream>>>(X, Yb, zpad, hTg);
  proj_g<128, false><<<gx, 512, 0, stream>>>(hTg, Wrub, bru, hx, zpad, XC, ub, nullptr);

  // round 2
  gemm_bt<false><<<gg, 256, 0, stream>>>(XC, 0, Abf, nullptr, Yb, 2 * RN);
  gemm_bt<true ><<<gg, 256, 0, stream>>>(Yb, 2 * RN, Abf, XC, Yb + RN, 2 * RN);
  xpose_h<<<gx, 256, 0, stream>>>(XC, Yb, zpad, hTg);
  proj_g<64, true><<<gx, 512, 0, stream>>>(hTg, WCb, bC, hx, zpad, nullptr, ub, out);
}

// Round 5
// 407.719 us; speedup vs baseline: 1.4947x; 1.1939x over previous
//
#include <hip/hip_runtime.h>

using u16 = unsigned short;
using u32 = unsigned int;
typedef __attribute__((ext_vector_type(8))) __bf16 bf16x8;
typedef __attribute__((ext_vector_type(8))) u16 u16x8;
typedef __attribute__((ext_vector_type(4))) float f32x4;

#define DEVI __device__ __forceinline__

constexpr int BN_ = 128;              // batch
constexpr int NN  = 1024;             // graph nodes
constexpr int CH  = 66;               // IN_DIM + HID
constexpr int HD  = 64;               // HID
constexpr int RR  = BN_ * CH;         // 8448 rows
constexpr long RN = (long)RR * NN;    // elements per part
constexpr int KTRUE = 330, KPAD = 352;
constexpr long M2 = (long)NN * NN;

DEVI float bf2f(u16 u) { u32 i = ((u32)u) << 16; float f; __builtin_memcpy(&f, &i, 4); return f; }
DEVI u16 f2bf(float f) { u32 i; __builtin_memcpy(&i, &f, 4); i += 0x7fffu + ((i >> 16) & 1u); return (u16)(i >> 16); }

DEVI void gl_lds16(const void* g, void* l) {
  __builtin_amdgcn_global_load_lds((const __attribute__((address_space(1))) u32*)g,
                                   (__attribute__((address_space(3))) u32*)l, 16, 0, 0);
}

// ---- GEMM:  Y[r,m] = sum_n X[r,n]*A[m,n]   (CHEB: Y = 2*that - X0) ----
// VALIDATED structure (round 1/4). Round-5 change: 1-D grid + bijective
// chunked XCD swizzle (1056 = 8 XCD x 132) so each XCD's L2 keeps its A-tile
// resident and streams a contiguous tm-range of X.
template<bool CHEB>
__global__ __launch_bounds__(256, 2)
void gemm_bt(const u16* __restrict__ Xb, long xz,
             const u16* __restrict__ Ab,
             const u16* __restrict__ X0,
             u16* __restrict__ Yb, long yz)
{
  __shared__ u16 Xs[128 * 32];
  __shared__ u16 Bs[128 * 32];
  // swizzle: consecutive hardware blocks round-robin XCDs; give XCD x the
  // contiguous wg range [x*132, (x+1)*132)  (528 = 4*132 so no z-crossing)
  const int bid = blockIdx.x;
  const int wg  = (bid & 7) * 132 + (bid >> 3);
  const int z   = wg >= 528;
  const int rem = wg - z * 528;
  const int tm  = rem >> 3, tn = rem & 7;

  const u16* X = Xb + (long)z * xz;
  const u16* A = Ab + (long)z * M2;
  u16*       Y = Yb + (long)z * yz;
  const int tid = threadIdx.x, wv = tid >> 6, ln = tid & 63;

  const int r0  = wv * 16 + (ln >> 2);
  const int kch = (((ln & 3) ^ ((r0 >> 1) & 3))) * 8;
  const u16* gX = X + (long)(tm * 128 + r0) * NN + kch;
  const u16* gA = A + (long)(tn * 128 + r0) * NN + kch;
  u16* lX = &Xs[wv * 512];
  u16* lA = &Bs[wv * 512];

  const int frow = ln & 15;
  const int fk   = ((ln >> 4) ^ ((ln >> 1) & 3)) * 8;
  const int wr = wv >> 1, wc = wv & 1;

  f32x4 acc[4][4] = {};

  for (int k0 = 0; k0 < NN; k0 += 32) {
    gl_lds16(gX + k0,            lX);
    gl_lds16(gX + k0 + 64 * NN,  lX + 2048);
    gl_lds16(gA + k0,            lA);
    gl_lds16(gA + k0 + 64 * NN,  lA + 2048);
    __syncthreads();
    bf16x8 af[4], bfv[4];
#pragma unroll
    for (int m = 0; m < 4; m++) af[m]  = *(const bf16x8*)&Xs[(wr * 64 + m * 16 + frow) * 32 + fk];
#pragma unroll
    for (int n = 0; n < 4; n++) bfv[n] = *(const bf16x8*)&Bs[(wc * 64 + n * 16 + frow) * 32 + fk];
#pragma unroll
    for (int m = 0; m < 4; m++)
#pragma unroll
      for (int n = 0; n < 4; n++)
        acc[m][n] = __builtin_amdgcn_mfma_f32_16x16x32_bf16(af[m], bfv[n], acc[m][n], 0, 0, 0);
    __syncthreads();
  }

  const int colb = tn * 128 + wc * 64 + frow;
  const int rowb = tm * 128 + wr * 64 + (ln >> 4) * 4;
#pragma unroll
  for (int m = 0; m < 4; m++)
#pragma unroll
    for (int n = 0; n < 4; n++) {
      const int col = colb + n * 16;
#pragma unroll
      for (int q = 0; q < 4; q++) {
        const long r = rowb + m * 16 + q;
        float v = acc[m][n][q];
        if (CHEB) v = 2.0f * v - bf2f(X0[r * NN + col]);
        Y[r * NN + col] = f2bf(v);
      }
    }
}

// ---- fused transpose + projection ----
// out[o,(b,n)] = act( sum_c W[o,c]*h[c,(b,n)] + bias[o] )
// Per block (b, 64-col tile): 4 sub-passes {hf: n-half, ch: c-half} each
// staging 176c x 32n c-major via gl_lds16 (xpose_h phase A, validated) then
// in-LDS transposing into LB[64][720B] (xpose_h phase B, validated); then
// MFMA from LB + fused epilogue (proj_g, validated). No hTg global round-trip.
template<int O, bool FINAL>
__global__ __launch_bounds__(512)
void proj_f(const u16* __restrict__ part0, const u16* __restrict__ Yb,
            const u16* __restrict__ W, const float* __restrict__ bias,
            const float* __restrict__ hx, const u16* __restrict__ zpad,
            u16* __restrict__ xcrow, float* __restrict__ ubuf,
            float* __restrict__ outp)
{
  __shared__ u16 LB[23040];   // 64 rows x 720B (704 data + 16 pad)
  __shared__ u16 LA[5632];    // 176c x 32n c-major, 11 x 1KB chunks
  const int b = blockIdx.y, n0 = blockIdx.x * 64;
  const int tid = threadIdx.x, wv = tid >> 6, ln = tid & 63;

  const int of  = (O == 128) ? wv : (wv >> 1);
  const int nfb = (O == 128) ? 0  : 2 * (wv & 1);
  constexpr int NF = (O == 128) ? 4 : 2;
  const int frow = ln & 15, klane = ln >> 4;

  // preload W frags to regs (L2-resident, overlaps with staging)
  const u16* wb = W + (long)(of * 16 + frow) * KPAD + klane * 8;
  bf16x8 wf[11];
#pragma unroll
  for (int t = 0; t < 11; ++t) wf[t] = *(const bf16x8*)(wb + t * 32);

  for (int hf = 0; hf < 2; ++hf)
#pragma unroll 1
    for (int ch = 0; ch < 2; ++ch) {
      // stage: chunk i = c-rows (ch*176 + 16i ..+15), 64B (32 n) per row
#pragma unroll
      for (int ii = 0; ii < 2; ++ii) {
        const int i = ii * 8 + wv;
        if (i < 11) {
          const int c = ch * 176 + 16 * i + (ln >> 2);
          const u16* src;
          if (c < KTRUE) {
            const int p = c / 66, f = c - 66 * p;
            const u16* base = (p == 0) ? part0 : (Yb + (long)(p - 1) * RN);
            src = base + (long)(b * CH + f) * NN + n0 + hf * 32 + (ln & 3) * 8;
          } else {
            src = zpad;
          }
          gl_lds16(src, (char*)LA + i * 1024);
        }
      }
      __syncthreads();
      // gather: thread (n, cch) packs 8 consecutive c into one b128 LB write
#pragma unroll
      for (int it = 0; it < 2; ++it) {
        const int q = it * 512 + tid;
        if (q < 704) {                      // 32 n x 22 c-chunks
          const int n = q & 31, cch = q >> 5;
          u16x8 v;
#pragma unroll
          for (int j = 0; j < 8; ++j) v[j] = LA[(cch * 8 + j) * 32 + n];
          *(u16x8*)((char*)LB + (hf * 32 + n) * 720 + ch * 352 + cch * 16) = v;
        }
      }
      __syncthreads();
    }

  f32x4 acc[NF] = {};
#pragma unroll
  for (int t = 0; t < 11; ++t) {
#pragma unroll
    for (int j = 0; j < NF; ++j) {
      const int nf = nfb + j;
      const bf16x8 bt = *(const bf16x8*)((char*)LB + (nf * 16 + frow) * 720 + t * 64 + klane * 16);
      acc[j] = __builtin_amdgcn_mfma_f32_16x16x32_bf16(wf[t], bt, acc[j], 0, 0, 0);
    }
  }

  const int orow = klane * 4;
#pragma unroll
  for (int j = 0; j < NF; ++j) {
    const int nf = nfb + j;
    const int ncol = n0 + nf * 16 + frow;
#pragma unroll
    for (int q = 0; q < 4; ++q) {
      const int o = of * 16 + orow + q;
      const float pre = acc[j][q] + bias[o];
      if (!FINAL) {
        const float sg = 1.0f / (1.0f + __expf(-pre));
        if (o < HD) {        // r-gate -> bf16(r*hx) into XC rows
          const float hv = hx[(long)(b * HD + o) * NN + ncol];
          xcrow[(long)(b * CH + 2 + o) * NN + ncol] = f2bf(sg * hv);
        } else {             // u-gate -> f32 (parked in d_out, reread by proj2)
          ubuf[(long)(b * HD + (o - HD)) * NN + ncol] = sg;
        }
      } else {
        const float e  = __expf(2.0f * pre);
        const float cc = 1.0f - 2.0f / (e + 1.0f);   // tanh(pre)
        const long oi = (long)(b * HD + o) * NN + ncol;
        const float u = ubuf[oi];
        outp[oi] = u * hx[oi] + (1.0f - u) * cc;
      }
    }
  }
}

// ---- build X = bf16([inputs; hx]) rows; also seed XC's input channels ----
__global__ void build_x(const float* __restrict__ inp, const float* __restrict__ hx,
                        u16* __restrict__ X, u16* __restrict__ XC)
{
  const int row = blockIdx.x;
  const int b = row / 66, f = row - b * 66;
  const int n0 = threadIdx.x * 4;
  const float* s = (f < 2) ? (inp + (long)(b * 2 + f) * NN) : (hx + (long)(b * HD + f - 2) * NN);
  const float4 v = *(const float4*)(s + n0);
  ushort4 o;
  o.x = f2bf(v.x); o.y = f2bf(v.y); o.z = f2bf(v.z); o.w = f2bf(v.w);
  *(ushort4*)&X[(long)row * NN + n0] = o;
  if (f < 2) *(ushort4*)&XC[(long)row * NN + n0] = o;
}

// ---- convert A0,A1 -> bf16; pad+convert W_ru,W_C to [O][352] bf16 ----
__global__ void prep(const float* __restrict__ A0, const float* __restrict__ A1,
                     const float* __restrict__ Wru, const float* __restrict__ WC,
                     u16* __restrict__ Abf, u16* __restrict__ Wrub, u16* __restrict__ WCb)
{
  const int gid = blockIdx.x * 256 + threadIdx.x;
  if (gid < 524288) {
    const float* s = (gid < 262144) ? (A0 + (long)gid * 4) : (A1 + (long)(gid - 262144) * 4);
    const float4 v = *(const float4*)s;
    ushort4 o; o.x = f2bf(v.x); o.y = f2bf(v.y); o.z = f2bf(v.z); o.w = f2bf(v.w);
    *(ushort4*)&Abf[(long)gid * 4] = o;
  } else if (gid < 524288 + 128 * KPAD) {
    const int g = gid - 524288;
    const int o = g / KPAD, c = g - o * KPAD;
    Wrub[g] = f2bf(c < KTRUE ? Wru[o * KTRUE + c] : 0.0f);
  } else if (gid < 524288 + 128 * KPAD + 64 * KPAD) {
    const int g = gid - 524288 - 128 * KPAD;
    const int o = g / KPAD, c = g - o * KPAD;
    WCb[g] = f2bf(c < KTRUE ? WC[o * KTRUE + c] : 0.0f);
  }
}

extern "C" void kernel_launch(void* const* d_in, const int* in_sizes, int n_in,
                              void* d_out, int out_size, void* d_ws, size_t ws_size,
                              hipStream_t stream)
{
  const float* inp = (const float*)d_in[0];
  const float* hx  = (const float*)d_in[1];
  const float* A0  = (const float*)d_in[2];
  const float* A1  = (const float*)d_in[3];
  const float* Wru = (const float*)d_in[4];
  const float* bru = (const float*)d_in[5];
  const float* WC  = (const float*)d_in[6];
  const float* bC  = (const float*)d_in[7];
  float* out = (float*)d_out;

  char* ws = (char*)d_ws;
  u16* Abf  = (u16*)(ws);                 //  4,194,304 B  [A0, A1] bf16
  u16* Wrub = (u16*)(ws + 4194304);       //     90,112 B  (128x352)
  u16* WCb  = (u16*)(ws + 4284416);       //     45,056 B  (64x352)
  u16* zpad = (u16*)(ws + 4329472);       //        256 B  zeros
  u16* X    = (u16*)(ws + 4329728);       // 17,301,504 B  (8448x1024 bf16 rows)
  u16* XC   = (u16*)(ws + 21631232);      // 17,301,504 B
  u16* Yb   = (u16*)(ws + 38932736);      // 69,206,016 B  (4 parts) -> 108,138,752 B
  float* ub = out;                        // u-gate parked in d_out between proj1/proj2

  hipMemsetAsync(zpad, 0, 256, stream);
  prep<<<2312, 256, 0, stream>>>(A0, A1, Wru, WC, Abf, Wrub, WCb);
  build_x<<<RR, 256, 0, stream>>>(inp, hx, X, XC);

  const dim3 gx(16, BN_);
  // round 1: parts [Y1_0, Y2_0, Y1_1, Y2_1]
  gemm_bt<false><<<1056, 256, 0, stream>>>(X, 0, Abf, nullptr, Yb, 2 * RN);
  gemm_bt<true ><<<1056, 256, 0, stream>>>(Yb, 2 * RN, Abf, X, Yb + RN, 2 * RN);
  proj_f<128, false><<<gx, 512, 0, stream>>>(X, Yb, Wrub, bru, hx, zpad, XC, ub, nullptr);

  // round 2
  gemm_bt<false><<<1056, 256, 0, stream>>>(XC, 0, Abf, nullptr, Yb, 2 * RN);
  gemm_bt<true ><<<1056, 256, 0, stream>>>(Yb, 2 * RN, Abf, XC, Yb + RN, 2 * RN);
  proj_f<64, true><<<gx, 512, 0, stream>>>(XC, Yb, WCb, bC, hx, zpad, nullptr, ub, out);
}

// Round 6
// 373.380 us; speedup vs baseline: 1.6321x; 1.0920x over previous
//
#include <hip/hip_runtime.h>

using u16 = unsigned short;
using u32 = unsigned int;
typedef __attribute__((ext_vector_type(8))) __bf16 bf16x8;
typedef __attribute__((ext_vector_type(8))) u16 u16x8;
typedef __attribute__((ext_vector_type(4))) float f32x4;

#define DEVI __device__ __forceinline__

constexpr int BN_ = 128;              // batch
constexpr int NN  = 1024;             // graph nodes
constexpr int CH  = 66;               // IN_DIM + HID
constexpr int HD  = 64;               // HID
constexpr int RR  = BN_ * CH;         // 8448 rows
constexpr long RN = (long)RR * NN;    // elements per part
constexpr int KTRUE = 330, KPAD = 352;
constexpr long M2 = (long)NN * NN;

DEVI float bf2f(u16 u) { u32 i = ((u32)u) << 16; float f; __builtin_memcpy(&f, &i, 4); return f; }
DEVI u16 f2bf(float f) { u32 i; __builtin_memcpy(&i, &f, 4); i += 0x7fffu + ((i >> 16) & 1u); return (u16)(i >> 16); }

DEVI void gl_lds16(const void* g, void* l) {
  __builtin_amdgcn_global_load_lds((const __attribute__((address_space(1))) u32*)g,
                                   (__attribute__((address_space(3))) u32*)l, 16, 0, 0);
}

// ---- GEMM (triple-buffered, counted vmcnt):  Y[r,col] = sum_n X[r,n]*A[col,n]
// SQ: Y = 2*acc - I  (computes B2 = 2*A*A^T' - I given A row-major + A^T)
// Index math / fragment layout identical to the validated round-1/4/5 kernel;
// only the K-loop schedule changed: 3 LDS buffers, prefetch distance 2,
// ONE raw s_barrier per K-step, s_waitcnt vmcnt(4) so the newest half-tile
// stays in flight across the barrier (T3/T4 minimum recipe; m135 ledger:
// at each wait, 4 loads (tile t+2) outstanding, tile t+1's 4 drained).
template<int TMZ, bool SQ>
__global__ __launch_bounds__(256, 2)
void gemm_db(const u16* __restrict__ Xb, long xzs,
             const u16* __restrict__ Ab, long azs,
             u16* __restrict__ Yb, long ozs)
{
  __shared__ u16 L[3 * 8192];   // 48 KB: 3 bufs x (X 8KB + B 8KB)
  // bijective chunked XCD swizzle: XCD x owns contiguous wg range
  const int bid = blockIdx.x;
  const int wg  = (bid & 7) * (gridDim.x >> 3) + (bid >> 3);
  const int z   = wg / TMZ;
  const int rem = wg - z * TMZ;
  const int tm  = rem >> 3, tn = rem & 7;

  const u16* X = Xb + (long)z * xzs;
  const u16* A = Ab + (long)z * azs;
  u16*       Y = Yb + (long)z * ozs;
  const int tid = threadIdx.x, wv = tid >> 6, ln = tid & 63;

  const int r0  = wv * 16 + (ln >> 2);
  const int kch = (((ln & 3) ^ ((r0 >> 1) & 3))) * 8;
  const u16* gX = X + (long)(tm * 128 + r0) * NN + kch;
  const u16* gA = A + (long)(tn * 128 + r0) * NN + kch;
  const int lofs = wv * 512;

  const int frow = ln & 15;
  const int fk   = ((ln >> 4) ^ ((ln >> 1) & 3)) * 8;
  const int wr = wv >> 1, wc = wv & 1;

  f32x4 acc[4][4] = {};

#define STAGE(T, BUF) do {                                  \
    u16* bx_ = &L[(BUF) * 8192 + lofs];                     \
    u16* bb_ = &L[(BUF) * 8192 + 4096 + lofs];              \
    const int k0_ = (T) * 32;                               \
    gl_lds16(gX + k0_,           bx_);                      \
    gl_lds16(gX + k0_ + 64 * NN, bx_ + 2048);               \
    gl_lds16(gA + k0_,           bb_);                      \
    gl_lds16(gA + k0_ + 64 * NN, bb_ + 2048);               \
  } while (0)

  // prologue: tiles 0,1 in flight; wait oldest 4 (tile 0) only
  STAGE(0, 0);
  STAGE(1, 1);
  asm volatile("s_waitcnt vmcnt(4)" ::: "memory");
  __builtin_amdgcn_s_barrier();
  __builtin_amdgcn_sched_barrier(0);

  int cur = 0;
  for (int t = 0; t < 32; ++t) {
    const int nx = (cur >= 1) ? cur - 1 : cur + 2;   // (cur+2)%3
    if (t + 2 < 32) STAGE(t + 2, nx);                // buf nx last read at t-1
    const u16* bx = &L[cur * 8192];
    const u16* bb = bx + 4096;
    bf16x8 af[4], bfv[4];
#pragma unroll
    for (int m = 0; m < 4; m++) af[m]  = *(const bf16x8*)&bx[(wr * 64 + m * 16 + frow) * 32 + fk];
#pragma unroll
    for (int n = 0; n < 4; n++) bfv[n] = *(const bf16x8*)&bb[(wc * 64 + n * 16 + frow) * 32 + fk];
#pragma unroll
    for (int m = 0; m < 4; m++)
#pragma unroll
      for (int n = 0; n < 4; n++)
        acc[m][n] = __builtin_amdgcn_mfma_f32_16x16x32_bf16(af[m], bfv[n], acc[m][n], 0, 0, 0);
    if (t < 31) {
      if (t + 2 < 32) asm volatile("s_waitcnt vmcnt(4)" ::: "memory");
      else            asm volatile("s_waitcnt vmcnt(0)" ::: "memory");
      __builtin_amdgcn_s_barrier();
      __builtin_amdgcn_sched_barrier(0);
    }
    cur = (cur >= 2) ? 0 : cur + 1;
  }
#undef STAGE

  // C/D layout: col = lane&15, row = (lane>>4)*4 + q   [validated]
  const int colb = tn * 128 + wc * 64 + frow;
  const int rowb = tm * 128 + wr * 64 + (ln >> 4) * 4;
#pragma unroll
  for (int m = 0; m < 4; m++)
#pragma unroll
    for (int n = 0; n < 4; n++) {
      const int col = colb + n * 16;
#pragma unroll
      for (int q = 0; q < 4; q++) {
        const long r = rowb + m * 16 + q;
        float v = acc[m][n][q];
        if (SQ) v = 2.0f * v - (r == col ? 1.0f : 0.0f);
        Y[r * NN + col] = f2bf(v);
      }
    }
}

// ---- fused transpose + projection (VALIDATED round 5 — unchanged) ----
template<int O, bool FINAL>
__global__ __launch_bounds__(512)
void proj_f(const u16* __restrict__ part0, const u16* __restrict__ Yb,
            const u16* __restrict__ W, const float* __restrict__ bias,
            const float* __restrict__ hx, const u16* __restrict__ zpad,
            u16* __restrict__ xcrow, float* __restrict__ ubuf,
            float* __restrict__ outp)
{
  __shared__ u16 LB[23040];   // 64 rows x 720B (704 data + 16 pad)
  __shared__ u16 LA[5632];    // 176c x 32n c-major, 11 x 1KB chunks
  const int b = blockIdx.y, n0 = blockIdx.x * 64;
  const int tid = threadIdx.x, wv = tid >> 6, ln = tid & 63;

  const int of  = (O == 128) ? wv : (wv >> 1);
  const int nfb = (O == 128) ? 0  : 2 * (wv & 1);
  constexpr int NF = (O == 128) ? 4 : 2;
  const int frow = ln & 15, klane = ln >> 4;

  const u16* wb = W + (long)(of * 16 + frow) * KPAD + klane * 8;
  bf16x8 wf[11];
#pragma unroll
  for (int t = 0; t < 11; ++t) wf[t] = *(const bf16x8*)(wb + t * 32);

  for (int hf = 0; hf < 2; ++hf)
#pragma unroll 1
    for (int ch = 0; ch < 2; ++ch) {
#pragma unroll
      for (int ii = 0; ii < 2; ++ii) {
        const int i = ii * 8 + wv;
        if (i < 11) {
          const int c = ch * 176 + 16 * i + (ln >> 2);
          const u16* src;
          if (c < KTRUE) {
            const int p = c / 66, f = c - 66 * p;
            const u16* base = (p == 0) ? part0 : (Yb + (long)(p - 1) * RN);
            src = base + (long)(b * CH + f) * NN + n0 + hf * 32 + (ln & 3) * 8;
          } else {
            src = zpad;
          }
          gl_lds16(src, (char*)LA + i * 1024);
        }
      }
      __syncthreads();
#pragma unroll
      for (int it = 0; it < 2; ++it) {
        const int q = it * 512 + tid;
        if (q < 704) {
          const int n = q & 31, cch = q >> 5;
          u16x8 v;
#pragma unroll
          for (int j = 0; j < 8; ++j) v[j] = LA[(cch * 8 + j) * 32 + n];
          *(u16x8*)((char*)LB + (hf * 32 + n) * 720 + ch * 352 + cch * 16) = v;
        }
      }
      __syncthreads();
    }

  f32x4 acc[NF] = {};
#pragma unroll
  for (int t = 0; t < 11; ++t) {
#pragma unroll
    for (int j = 0; j < NF; ++j) {
      const int nf = nfb + j;
      const bf16x8 bt = *(const bf16x8*)((char*)LB + (nf * 16 + frow) * 720 + t * 64 + klane * 16);
      acc[j] = __builtin_amdgcn_mfma_f32_16x16x32_bf16(wf[t], bt, acc[j], 0, 0, 0);
    }
  }

  const int orow = klane * 4;
#pragma unroll
  for (int j = 0; j < NF; ++j) {
    const int nf = nfb + j;
    const int ncol = n0 + nf * 16 + frow;
#pragma unroll
    for (int q = 0; q < 4; ++q) {
      const int o = of * 16 + orow + q;
      const float pre = acc[j][q] + bias[o];
      if (!FINAL) {
        const float sg = 1.0f / (1.0f + __expf(-pre));
        if (o < HD) {
          const float hv = hx[(long)(b * HD + o) * NN + ncol];
          xcrow[(long)(b * CH + 2 + o) * NN + ncol] = f2bf(sg * hv);
        } else {
          ubuf[(long)(b * HD + (o - HD)) * NN + ncol] = sg;
        }
      } else {
        const float e  = __expf(2.0f * pre);
        const float cc = 1.0f - 2.0f / (e + 1.0f);
        const long oi = (long)(b * HD + o) * NN + ncol;
        const float u = ubuf[oi];
        outp[oi] = u * hx[oi] + (1.0f - u) * cc;
      }
    }
  }
}

// ---- build X = bf16([inputs; hx]) rows; also seed XC's input channels ----
__global__ void build_x(const float* __restrict__ inp, const float* __restrict__ hx,
                        u16* __restrict__ X, u16* __restrict__ XC)
{
  const int row = blockIdx.x;
  const int b = row / 66, f = row - b * 66;
  const int n0 = threadIdx.x * 4;
  const float* s = (f < 2) ? (inp + (long)(b * 2 + f) * NN) : (hx + (long)(b * HD + f - 2) * NN);
  const float4 v = *(const float4*)(s + n0);
  ushort4 o;
  o.x = f2bf(v.x); o.y = f2bf(v.y); o.z = f2bf(v.z); o.w = f2bf(v.w);
  *(ushort4*)&X[(long)row * NN + n0] = o;
  if (f < 2) *(ushort4*)&XC[(long)row * NN + n0] = o;
}

// ---- A (f32, [m][n]) -> AT (bf16, [n][m])  (VALIDATED round 2) ----
__global__ void xposeA(const float* __restrict__ A0, const float* __restrict__ A1,
                       u16* __restrict__ AT)
{
  __shared__ float Ls[64][65];
  const int z = blockIdx.z;
  const float* A = z ? A1 : A0;
  u16* out = AT + (long)z * M2;
  const int m0 = blockIdx.y * 64, n0 = blockIdx.x * 64;
  const int t = threadIdx.x;
  const int rr = t >> 6, cc = t & 63;
#pragma unroll
  for (int i = 0; i < 16; i++)
    Ls[i * 4 + rr][cc] = A[(long)(m0 + i * 4 + rr) * NN + n0 + cc];
  __syncthreads();
  const int n = t >> 2, mc = (t & 3) * 16;
  u16 tmp[16];
#pragma unroll
  for (int k = 0; k < 16; k++) tmp[k] = f2bf(Ls[mc + k][n]);
  u16* dst = &out[(long)(n0 + n) * NN + m0 + mc];
  *(ushort4*)(dst + 0)  = *(ushort4*)&tmp[0];
  *(ushort4*)(dst + 4)  = *(ushort4*)&tmp[4];
  *(ushort4*)(dst + 8)  = *(ushort4*)&tmp[8];
  *(ushort4*)(dst + 12) = *(ushort4*)&tmp[12];
}

// ---- convert A0->slot0, A1->slot2 of Abf2; pad+convert W's (VALIDATED r2) ----
__global__ void prep(const float* __restrict__ A0, const float* __restrict__ A1,
                     const float* __restrict__ Wru, const float* __restrict__ WC,
                     u16* __restrict__ Abf2, u16* __restrict__ Wrub, u16* __restrict__ WCb)
{
  const int gid = blockIdx.x * 256 + threadIdx.x;
  if (gid < 524288) {
    const bool sec = gid >= 262144;
    const float* s = sec ? (A1 + (long)(gid - 262144) * 4) : (A0 + (long)gid * 4);
    u16* d = sec ? (Abf2 + 2 * M2 + (long)(gid - 262144) * 4) : (Abf2 + (long)gid * 4);
    const float4 v = *(const float4*)s;
    ushort4 o; o.x = f2bf(v.x); o.y = f2bf(v.y); o.z = f2bf(v.z); o.w = f2bf(v.w);
    *(ushort4*)d = o;
  } else if (gid < 524288 + 128 * KPAD) {
    const int g = gid - 524288;
    const int o = g / KPAD, c = g - o * KPAD;
    Wrub[g] = f2bf(c < KTRUE ? Wru[o * KTRUE + c] : 0.0f);
  } else if (gid < 524288 + 128 * KPAD + 64 * KPAD) {
    const int g = gid - 524288 - 128 * KPAD;
    const int o = g / KPAD, c = g - o * KPAD;
    WCb[g] = f2bf(c < KTRUE ? WC[o * KTRUE + c] : 0.0f);
  }
}

extern "C" void kernel_launch(void* const* d_in, const int* in_sizes, int n_in,
                              void* d_out, int out_size, void* d_ws, size_t ws_size,
                              hipStream_t stream)
{
  const float* inp = (const float*)d_in[0];
  const float* hx  = (const float*)d_in[1];
  const float* A0  = (const float*)d_in[2];
  const float* A1  = (const float*)d_in[3];
  const float* Wru = (const float*)d_in[4];
  const float* bru = (const float*)d_in[5];
  const float* WC  = (const float*)d_in[6];
  const float* bC  = (const float*)d_in[7];
  float* out = (float*)d_out;

  char* ws = (char*)d_ws;
  u16* Abf2 = (u16*)(ws);                 //  8,388,608 B  [A0, B2_0, A1, B2_1]
  u16* ATbf = (u16*)(ws + 8388608);       //  4,194,304 B  [A0^T, A1^T]
  u16* Wrub = (u16*)(ws + 12582912);      //     90,112 B  (128x352)
  u16* WCb  = (u16*)(ws + 12673024);      //     45,056 B  (64x352)
  u16* zpad = (u16*)(ws + 12718080);      //        256 B  zeros
  u16* X    = (u16*)(ws + 12718336);      // 17,301,504 B
  u16* XC   = (u16*)(ws + 30019840);      // 17,301,504 B
  u16* Yb   = (u16*)(ws + 47321344);      // 69,206,016 B  (4 parts) -> 116,527,360 B
  float* ub = out;                        // u-gate parked in d_out between proj1/proj2

  hipMemsetAsync(zpad, 0, 256, stream);
  prep<<<2312, 256, 0, stream>>>(A0, A1, Wru, WC, Abf2, Wrub, WCb);
  xposeA<<<dim3(16, 16, 2), 256, 0, stream>>>(A0, A1, ATbf);
  build_x<<<RR, 256, 0, stream>>>(inp, hx, X, XC);

  // B2_z = 2*A_z*A_z - I  into Abf2 slots 1,3 (numerics validated round 2)
  gemm_db<64, true><<<128, 256, 0, stream>>>(Abf2, 2 * M2, ATbf, M2, Abf2 + M2, 2 * M2);

  const dim3 gx(16, BN_);
  // round 1: one z=4 dispatch -> parts [Y1_0, Y2_0, Y1_1, Y2_1]
  gemm_db<528, false><<<2112, 256, 0, stream>>>(X, 0, Abf2, M2, Yb, RN);
  proj_f<128, false><<<gx, 512, 0, stream>>>(X, Yb, Wrub, bru, hx, zpad, XC, ub, nullptr);

  // round 2
  gemm_db<528, false><<<2112, 256, 0, stream>>>(XC, 0, Abf2, M2, Yb, RN);
  proj_f<64, true><<<gx, 512, 0, stream>>>(XC, Yb, WCb, bC, hx, zpad, nullptr, ub, out);
}